// Round 13
// baseline (296.809 us; speedup 1.0000x reference)
//
#include <hip/hip_runtime.h>

// GraphConv: out[t] += input[s] * (esgn*enorm), 3.2M edges, 100K nodes, D=32 fp32.
// Round 13: nodesort parallelized 4x. R12's coalesced copy-out was neutral ->
// partition copy wasn't the hog (reverted). nodesort2 ran only 196 blocks on
// 256 CUs; now each bucket is split across SUB=4 sub-blocks (784 blocks), each
// owning 128 nodes: stream bucket recs (L2-hot), filtered LDS hist, wave-reduced
// 'below' count for the sub-base, filtered scatter into a 32KB window.
// Pipeline: bhist(LDS) -> bscan -> partition (R11, verified) -> nodesort3
//   -> seg_accum (atomic-free, ~70us = near gather ceiling).

#define NB   256
#define MAXK 256          // max buckets (span 512 -> n_nodes <= 131072)
#define SPAN_SHIFT 9
#define SPAN 512
#define PT   7680         // partition tile edges; srec = 60KB LDS
#define SUB  4
#define SUBSPAN (SPAN / SUB)   // 128 nodes per sub-block

// Bucket-level histogram: LDS counters, one global atomic per bucket/block.
__global__ __launch_bounds__(NB) void bhist_kernel(
    const int* __restrict__ tidx, int* __restrict__ bcnt, int n_edges)
{
    __shared__ int lh[MAXK];
    for (int i = threadIdx.x; i < MAXK; i += NB) lh[i] = 0;
    __syncthreads();
    int stride = gridDim.x * NB;
    for (int e = blockIdx.x * NB + threadIdx.x; e < n_edges; e += stride)
        atomicAdd(&lh[tidx[e] >> SPAN_SHIFT], 1);
    __syncthreads();
    for (int i = threadIdx.x; i < MAXK; i += NB)
        if (lh[i]) atomicAdd(&bcnt[i], lh[i]);
}

// Exclusive scan over MAXK bucket counts -> bbase[0..MAXK], bcur=bbase.
__global__ __launch_bounds__(MAXK) void bscan_kernel(
    const int* __restrict__ bcnt, int* __restrict__ bbase, int* __restrict__ bcur)
{
    __shared__ int part[MAXK];
    int t = threadIdx.x;
    int c = bcnt[t];
    part[t] = c;
    __syncthreads();
    for (int off = 1; off < MAXK; off <<= 1) {
        int v = (t >= off) ? part[t - off] : 0;
        __syncthreads();
        part[t] += v;
        __syncthreads();
    }
    int excl = part[t] - c;
    bbase[t] = excl;
    bcur[t] = excl;
    if (t == MAXK - 1) bbase[MAXK] = part[MAXK - 1];
}

// R11 partition (verified): tile-local bucket sort in LDS, per-bucket run copy.
__global__ __launch_bounds__(NB) void partition_kernel(
    const int* __restrict__ sidx, const int* __restrict__ tidx,
    const float* __restrict__ enorm, const float* __restrict__ esgn,
    int* __restrict__ bcur, int2* __restrict__ recs, int n_edges)
{
    __shared__ int2 srec[PT];              // 60 KB
    __shared__ int lh[MAXK];
    __shared__ int lbase[MAXK];
    __shared__ int lcur[MAXK];
    __shared__ int gb[MAXK];
    int t = threadIdx.x;
    lh[t] = 0;
    __syncthreads();

    size_t tb = (size_t)blockIdx.x * PT;
    for (int j = 0; j < PT / NB; ++j) {
        int e = (int)tb + j * NB + t;
        if (e < n_edges) atomicAdd(&lh[tidx[e] >> SPAN_SHIFT], 1);
    }
    __syncthreads();
    int c = lh[t];
    lbase[t] = c;
    __syncthreads();
    for (int off = 1; off < MAXK; off <<= 1) {
        int v = (t >= off) ? lbase[t - off] : 0;
        __syncthreads();
        lbase[t] += v;
        __syncthreads();
    }
    int excl = lbase[t] - c;
    __syncthreads();
    lbase[t] = excl;
    lcur[t] = excl;
    if (c > 0) gb[t] = atomicAdd(&bcur[t], c);
    __syncthreads();
    for (int j = 0; j < PT / NB; ++j) {
        int e = (int)tb + j * NB + t;
        if (e < n_edges) {
            int tn = tidx[e];
            int b = tn >> SPAN_SHIFT;
            unsigned rec = ((unsigned)sidx[e] << SPAN_SHIFT) | (unsigned)(tn & (SPAN - 1));
            float w = enorm[e] * esgn[e];
            int p = atomicAdd(&lcur[b], 1);
            srec[p] = make_int2((int)rec, __float_as_int(w));
        }
    }
    __syncthreads();
    int cnt = lh[t];
    if (cnt > 0) {
        int lb = lbase[t];
        int g = gb[t];
        for (int i = 0; i < cnt; ++i) recs[g + i] = srec[lb + i];
    }
}

// Per-(bucket, sub-range) node hist + scan + scatter. blockIdx = b*SUB + j;
// sub-block j owns local nodes [j*128, (j+1)*128). Streams the bucket's recs
// (L2-hot), filters. 'below' = recs in lower sub-ranges -> global sub-base.
__global__ __launch_bounds__(1024) void nodesort3_kernel(
    const int2* __restrict__ recs, const int* __restrict__ bbase,
    int* __restrict__ nodeoff, int2* __restrict__ sorted, int n_nodes, int K)
{
    __shared__ int lcnt[SUBSPAN];
    __shared__ int lpart[SUBSPAN];
    __shared__ int lcur[SUBSPAN];
    __shared__ int below_sh;
    int blk = blockIdx.x;
    int b = blk / SUB;
    int j = blk - b * SUB;
    int t = threadIdx.x;
    int lo = j * SUBSPAN;                  // local node range [lo, lo+SUBSPAN)
    int base_node = (b << SPAN_SHIFT) + lo;
    int bstart = bbase[b], bend = bbase[b + 1];

    if (t == 0) below_sh = 0;
    for (int i = t; i < SUBSPAN; i += 1024) lcnt[i] = 0;
    __syncthreads();

    int below = 0;
    for (int i = bstart + t; i < bend; i += 1024) {
        int ln = recs[i].x & (SPAN - 1);
        if ((ln - lo) >= 0 && (ln - lo) < SUBSPAN) atomicAdd(&lcnt[ln - lo], 1);
        else if (ln < lo) ++below;
    }
    // wave-reduce 'below', one LDS atomic per wave
    for (int off = 32; off > 0; off >>= 1) below += __shfl_down(below, off, 64);
    if ((t & 63) == 0 && below) atomicAdd(&below_sh, below);
    __syncthreads();
    int sub_base = bstart + below_sh;

    // exclusive scan over SUBSPAN=128 counters
    int c = (t < SUBSPAN) ? lcnt[t] : 0;
    if (t < SUBSPAN) lpart[t] = c;
    __syncthreads();
    for (int off = 1; off < SUBSPAN; off <<= 1) {
        int v = (t < SUBSPAN && t >= off) ? lpart[t - off] : 0;
        __syncthreads();
        if (t < SUBSPAN) lpart[t] += v;
        __syncthreads();
    }
    if (t < SUBSPAN) {
        int excl = lpart[t] - c;
        int node = base_node + t;
        int gpos = sub_base + excl;
        lcur[t] = gpos;
        if (node < n_nodes) nodeoff[node] = gpos;
    }
    if (b == K - 1 && j == SUB - 1 && t == 0) nodeoff[n_nodes] = bend;
    __syncthreads();
    // filtered scatter into this sub-range's ~32KB window
    for (int i = bstart + t; i < bend; i += 1024) {
        int2 r = recs[i];
        int ln = r.x & (SPAN - 1);
        if ((ln - lo) >= 0 && (ln - lo) < SUBSPAN) {
            int pos = atomicAdd(&lcur[ln - lo], 1);
            sorted[pos] = r;
        }
    }
}

// Segmented accumulate: 8 lanes per node, float4 per lane; no atomics.
__global__ __launch_bounds__(NB) void seg_accum(
    const float* __restrict__ input, const int2* __restrict__ sorted,
    const int* __restrict__ nodeoff, float* __restrict__ out, int n_nodes)
{
    int n = blockIdx.x * 32 + (threadIdx.x >> 3);
    int lane = threadIdx.x & 7;
    if (n >= n_nodes) return;
    int beg = nodeoff[n], end = nodeoff[n + 1];
    float4 acc = make_float4(0.f, 0.f, 0.f, 0.f);
    for (int i = beg; i < end; ++i) {
        int2 r = sorted[i];                       // broadcast within group
        float w = __int_as_float(r.y);
        int s = (int)(((unsigned)r.x) >> SPAN_SHIFT);
        float4 v = ((const float4*)(input + (size_t)s * 32))[lane];
        acc.x = fmaf(w, v.x, acc.x);
        acc.y = fmaf(w, v.y, acc.y);
        acc.z = fmaf(w, v.z, acc.z);
        acc.w = fmaf(w, v.w, acc.w);
    }
    ((float4*)(out + (size_t)n * 32))[lane] = acc;
}

// Last-resort fallback (R3): direct atomic scatter.
__global__ __launch_bounds__(NB) void graphconv_scatter(
    const float* __restrict__ input, const int* __restrict__ sidx,
    const int* __restrict__ tidx, const float* __restrict__ enorm,
    const float* __restrict__ esgn, float* __restrict__ out, int n_edges)
{
    int t = blockIdx.x * NB + threadIdx.x;
    int e = t >> 3;
    int sub = t & 7;
    if (e >= n_edges) return;
    int s = sidx[e];
    int d = tidx[e];
    float w = enorm[e] * esgn[e];
    const float4* src = (const float4*)(input + (size_t)s * 32);
    float4 v = src[sub];
    float* op = out + (size_t)d * 32 + sub * 4;
    atomicAdd(op + 0, v.x * w);
    atomicAdd(op + 1, v.y * w);
    atomicAdd(op + 2, v.z * w);
    atomicAdd(op + 3, v.w * w);
}

extern "C" void kernel_launch(void* const* d_in, const int* in_sizes, int n_in,
                              void* d_out, int out_size, void* d_ws, size_t ws_size,
                              hipStream_t stream) {
    const float* input = (const float*)d_in[0];
    const int*   eidx  = (const int*)d_in[1];   // int64 in reference -> int32 here
    const float* enorm = (const float*)d_in[2];
    const float* esgn  = (const float*)d_in[3];
    float*       out   = (float*)d_out;

    int n_edges = in_sizes[1] / 2;             // eidx is (2, n_edges)
    int n_nodes = in_sizes[0] / 32;            // input is (n_nodes, 32)
    const int* sidx = eidx;
    const int* tidx = eidx + n_edges;

    int K = (n_nodes + SPAN - 1) >> SPAN_SHIFT;   // 196

    // Workspace: sorted[E int2] | recs[E int2] | nodeoff[n+1]
    //            | bcnt[MAXK] | bbase[MAXK+1] | bcur[MAXK]
    size_t need = (size_t)n_edges * 16 +
                  ((size_t)n_nodes + 1 + 3 * MAXK + 1) * 4;

    if (ws_size >= need && K <= MAXK) {
        int2* sorted  = (int2*)d_ws;
        int2* recs    = sorted + n_edges;
        int*  nodeoff = (int*)(recs + n_edges);
        int*  bcnt    = nodeoff + (n_nodes + 1);
        int*  bbase   = bcnt + MAXK;
        int*  bcur    = bbase + (MAXK + 1);

        hipMemsetAsync(bcnt, 0, MAXK * sizeof(int), stream);

        bhist_kernel    <<<1024, NB,   0, stream>>>(tidx, bcnt, n_edges);
        bscan_kernel    <<<1,    MAXK, 0, stream>>>(bcnt, bbase, bcur);
        int pg = (n_edges + PT - 1) / PT;
        partition_kernel<<<pg,   NB,   0, stream>>>(sidx, tidx, enorm, esgn,
                                                    bcur, recs, n_edges);
        nodesort3_kernel<<<K * SUB, 1024, 0, stream>>>(recs, bbase, nodeoff,
                                                       sorted, n_nodes, K);
        int ag = (n_nodes + 31) / 32;
        seg_accum       <<<ag,   NB,   0, stream>>>(input, sorted, nodeoff,
                                                    out, n_nodes);
    } else {
        hipMemsetAsync(d_out, 0, (size_t)out_size * sizeof(float), stream);
        size_t threads_total = (size_t)n_edges * 8;
        int grid = (int)((threads_total + NB - 1) / NB);
        graphconv_scatter<<<grid, NB, 0, stream>>>(input, sidx, tidx, enorm, esgn,
                                                   out, n_edges);
    }
}